// Round 6
// baseline (38.231 us; speedup 1.0000x reference)
//
#include <hip/hip_runtime.h>

// PixelEffectModule: 8-bin intensity histogram over 11x11 windows at stride 8,
// argmax bin, output that bin's mean RGB, upsampled 8x8.
// Input: rgb (1,3,2048,2048) fp32 in [0,255). Output: (1,3,2048,2048) fp32.
//
// R6 = R4's verified skeleton (4 row-band waves/cell-strip, two-row writes,
// identical edge masks + argmax) with two audited deltas:
//  1) single-pass: per-bin r/g/b sums accumulated by 8-way predicated FMA
//     (static indexing, 24 regs), published to LDS [part][bin][lane] so the
//     runtime-best read is bank-conflict-free (bank = lane&31 for any best).
//     Removes pass-2 global re-reads (R4's FETCH inflation).
//  2) XCD-aware bijective swizzle: slot=(wgid&7)*128+(wgid>>3), so each XCD
//     owns 32 contiguous cell-rows and window-overlap rows hit its L2.

#define Wd 2048
#define Hd 2048
#define HW (Wd * Hd)

typedef unsigned int u32;
typedef unsigned long long u64;

// correctly-rounded t/3 (Markstein), 3 ops vs ~9-inst div expansion
__device__ __forceinline__ float div3(float t) {
    const float c = 0x1.555556p-2f;  // RN(1/3)
    float q0 = t * c;
    float r  = __builtin_fmaf(q0, -3.0f, t);
    return __builtin_fmaf(r, c, q0);
}

__global__ __launch_bounds__(256, 4)
void pixel_effect_kernel(const float* __restrict__ rgb, float* __restrict__ out) {
    const int lx = threadIdx.x;          // cell lane 0..63
    const int p  = threadIdx.y;          // row-band part 0..3 (= wave index)

    // XCD swizzle: grid=1024 (multiple of 8) -> bijective. XCD (wgid&7) gets
    // slots [128*xcd, 128*xcd+128) = 32 contiguous cell-rows.
    u32 wgid = blockIdx.x;
    u32 slot = (wgid & 7u) * 128u + (wgid >> 3);
    const int oy = (int)(slot >> 2);
    const int bx = (int)(slot & 3u);
    const int ox = bx * 64 + lx;

    const float* Rp = rgb;
    const float* Gp = rgb + HW;
    const float* Bp = rgb + 2 * HW;

    // slot j maps x = xbase + j. Interior: xbase=8*(ox-1), valid j in [3,13].
    // ox==0: xbase=0, valid j in [0,5]. Loads (4 quads/ch) always in bounds.
    const int xbase = (ox == 0) ? 0 : ox * 8 - 8;
    const u32 vmask = (ox == 0) ? 0x003Fu : 0x3FF8u;
    const int ytop  = oy * 8 - 5;
    const int rbase = p * 3;             // first window-row of this band
    const int nr    = (p < 3) ? 3 : 2;   // rows per band: 3/3/3/2

    __shared__ u64   sc[4][64];          // packed byte counts per part
    __shared__ float ssr[4][8][64];      // per part, bin, lane: r-sum
    __shared__ float ssg[4][8][64];
    __shared__ float ssb[4][8][64];

    u64 c64 = 0;
    float sR[8], sG[8], sB[8];
#pragma unroll
    for (int b = 0; b < 8; ++b) { sR[b] = 0.f; sG[b] = 0.f; sB[b] = 0.f; }

    // ---- single pass: bin pixels, count + per-bin predicated sums ----
#pragma unroll
    for (int k = 0; k < 3; ++k) {
        int y = ytop + rbase + k;        // wave-uniform; only top edge clips
        if (k < nr && y >= 0) {
            int off = y * Wd + xbase;
            float vR[16], vG[16], vB[16];
#pragma unroll
            for (int q = 0; q < 4; ++q) {
                *(float4*)(vR + 4 * q) = *(const float4*)(Rp + off + 4 * q);
                *(float4*)(vG + 4 * q) = *(const float4*)(Gp + off + 4 * q);
                *(float4*)(vB + 4 * q) = *(const float4*)(Bp + off + 4 * q);
            }
#pragma unroll
            for (int j = 0; j < 14; ++j) {
                float m = div3(vR[j] + vG[j] + vB[j]);
                u32 bin = (u32)(m * 0.03125f);       // trunc(mean/32), exact
                u32 valid = (vmask >> j) & 1u;
                c64 += (u64)valid << (bin << 3);
                u32 binv = valid ? bin : 15u;        // 15 matches no bin
#pragma unroll
                for (int b = 0; b < 8; ++b) {
                    float hm = (binv == (u32)b) ? 1.0f : 0.0f;
                    sR[b] = __builtin_fmaf(hm, vR[j], sR[b]);
                    sG[b] = __builtin_fmaf(hm, vG[j], sG[b]);
                    sB[b] = __builtin_fmaf(hm, vB[j], sB[b]);
                }
            }
        }
    }
    sc[p][lx] = c64;
#pragma unroll
    for (int b = 0; b < 8; ++b) {
        ssr[p][b][lx] = sR[b];
        ssg[p][b][lx] = sG[b];
        ssb[p][b][lx] = sB[b];
    }
    __syncthreads();

    // ---- total counts + argmax (first-max wins, matches jnp.argmax) ----
    u64 tot = sc[0][lx] + sc[1][lx] + sc[2][lx] + sc[3][lx];  // bytes <=121
    u32 lo = (u32)tot, hi = (u32)(tot >> 32);
    u32 best = 0, bc = lo & 0xFFu;
#pragma unroll
    for (int b = 1; b < 8; ++b) {
        u32 cb = ((b < 4 ? lo : hi) >> ((b & 3) * 8)) & 0xFFu;
        bool t = cb > bc;
        bc   = t ? cb : bc;
        best = t ? (u32)b : best;
    }

    // ---- gather winning bin's sums (bank = lx&31 for any best: no conflict) ----
    int bi = (int)best;
    float tr = 0.f, tg = 0.f, tb = 0.f;
#pragma unroll
    for (int i = 0; i < 4; ++i) {
        tr += ssr[i][bi][lx];
        tg += ssg[i][bi][lx];
        tb += ssb[i][bi][lx];
    }
    float fbc = (float)bc;
    float orv = tr / fbc, ogv = tg / fbc, obv = tb / fbc;

    // ---- write: band p owns rows 2p, 2p+1 of the 8x8 block (as R4) ----
    size_t base = (size_t)(oy * 8 + p * 2) * Wd + (size_t)(ox * 8);
    float vals[3] = { orv, ogv, obv };
#pragma unroll
    for (int c = 0; c < 3; ++c) {
        float v = vals[c];
        float4 vv = make_float4(v, v, v, v);
        float* o0 = out + (size_t)c * HW + base;
        ((float4*)o0)[0] = vv;  ((float4*)o0)[1] = vv;
        float* o1 = o0 + Wd;
        ((float4*)o1)[0] = vv;  ((float4*)o1)[1] = vv;
    }
}

extern "C" void kernel_launch(void* const* d_in, const int* in_sizes, int n_in,
                              void* d_out, int out_size, void* d_ws, size_t ws_size,
                              hipStream_t stream) {
    const float* rgb = (const float*)d_in[0];
    float* out = (float*)d_out;
    dim3 block(64, 4, 1);                 // 4 waves; tid.y = row-band = wave idx
    dim3 grid(1024, 1, 1);                // 4 col-groups x 256 cell-rows (swizzled)
    hipLaunchKernelGGL(pixel_effect_kernel, grid, block, 0, stream, rgb, out);
}